// Round 11
// baseline (170.771 us; speedup 1.0000x reference)
//
#include <hip/hip_runtime.h>
#include <hip/hip_bf16.h>
#include <math.h>

// Problem: N=32768, M=8192, Z=64.  loss = mean_m min_n ||tanh(z_n) - e_m||^2
#define NN 32768
#define MM 8192
#define ZD 64
#define WAVES 4
#define MW 64                  // m-cols per wave (4 x 16-col MFMA tiles)
#define MBLK (WAVES * MW)      // 256 m-cols per block
#define NMB (MM / MBLK)        // 32 m-blocks
#define NCHUNKS 32             // split of N across chunks
#define CHUNK (NN / NCHUNKS)   // 1024
#define NROWS 128              // n-rows staged per iteration
#define NITER (CHUNK / NROWS)  // 8
#define GRID (NMB * NCHUNKS)   // 1024 blocks = 4/CU
#define SCALE 4294967296.0     // 2^32 fixed-point for deterministic sum

// counted vmcnt (T4): keep prefetch loads in flight ACROSS barriers;
// never drain to 0 in the main loop.
#define VMW(N) asm volatile("s_waitcnt vmcnt(" #N ")" ::: "memory")

typedef __attribute__((ext_vector_type(8))) short bf16x8;  // 8 bf16 = 4 VGPR
typedef __attribute__((ext_vector_type(4))) float f32x4;

__device__ inline unsigned short f2bf(float f) {  // RNE f32 -> bf16 (finite)
  unsigned u = __float_as_uint(f);
  return (unsigned short)((u + 0x7fffu + ((u >> 16) & 1u)) >> 16);
}
__device__ inline float bf2f(unsigned short h) {
  return __uint_as_float(((unsigned)h) << 16);
}

// ---------------------------------------------------------------------------
// prep (fused): blocks [0, NN/32) do z-rows; blocks [NN/32, ..) do e-rows and
// re-init dmin/acc/cnt (graph replays leave them dirty).
// ---------------------------------------------------------------------------
__global__ __launch_bounds__(256) void prep(
    const float* __restrict__ z, const float* __restrict__ e,
    unsigned short* __restrict__ zb, float* __restrict__ zn,
    unsigned short* __restrict__ eb, float* __restrict__ en,
    unsigned* __restrict__ dmin, unsigned long long* __restrict__ acc,
    unsigned* __restrict__ cnt) {
  const int q = threadIdx.x & 7;  // 8 f32 each
  if (blockIdx.x < NN / 32) {
    const int row = blockIdx.x * 32 + (threadIdx.x >> 3);
    const size_t base = (size_t)row * ZD + q * 8;
    float4 v0 = *reinterpret_cast<const float4*>(&z[base]);
    float4 v1 = *reinterpret_cast<const float4*>(&z[base + 4]);
    float in[8] = {v0.x, v0.y, v0.z, v0.w, v1.x, v1.y, v1.z, v1.w};
    unsigned short b[8];
    float s = 0.f;
#pragma unroll
    for (int i = 0; i < 8; ++i) {
      b[i] = f2bf(tanhf(in[i]));
      float r = bf2f(b[i]);
      s += r * r;
    }
    *reinterpret_cast<bf16x8*>(&zb[base]) = *reinterpret_cast<bf16x8*>(b);
    s += __shfl_xor(s, 1, 64);
    s += __shfl_xor(s, 2, 64);
    s += __shfl_xor(s, 4, 64);
    if (q == 0) zn[row] = s;
  } else {
    const int row = (blockIdx.x - NN / 32) * 32 + (threadIdx.x >> 3);
    const size_t base = (size_t)row * ZD + q * 8;
    float4 v0 = *reinterpret_cast<const float4*>(&e[base]);
    float4 v1 = *reinterpret_cast<const float4*>(&e[base + 4]);
    float in[8] = {v0.x, v0.y, v0.z, v0.w, v1.x, v1.y, v1.z, v1.w};
    unsigned short b[8];
    float s = 0.f;
#pragma unroll
    for (int i = 0; i < 8; ++i) {
      unsigned short qb = f2bf(in[i]);
      float r = bf2f(qb);
      s += r * r;
      b[i] = f2bf(-2.f * r);  // exact: power-of-2 scale + sign
    }
    *reinterpret_cast<bf16x8*>(&eb[base]) = *reinterpret_cast<bf16x8*>(b);
    s += __shfl_xor(s, 1, 64);
    s += __shfl_xor(s, 2, 64);
    s += __shfl_xor(s, 4, 64);
    if (q == 0) {
      en[row] = s;
      dmin[row] = 0xFFFFFFFFu;  // +inf key
    }
    if (blockIdx.x == NN / 32 && threadIdx.x == 0) {
      *acc = 0ULL;
      *cnt = 0u;
    }
  }
}

// ---------------------------------------------------------------------------
// min_dist: dmin[m] <- atomicMin over n of key( zn[n] - 2*z_n.e_m )
// R8 geometry (1024 blocks = 4/CU, 4 waves x 64 m-cols, 16x16x32 MFMA,
// XOR-swizzled LDS staging -> 0 conflicts, zn in the C-operand) + T4
// counted-vmcnt pipeline: raw s_barrier, vmcnt(4) mid-loop (stage for tile
// it+2 stays in flight across TWO compute iterations; __syncthreads' vmcnt(0)
// drain was ~40% idle cycles in R10). Compiler still auto-handles lgkmcnt
// for ds_read->MFMA (no hand-written ds asm).
// ---------------------------------------------------------------------------
__global__ __launch_bounds__(256) void min_dist(
    const unsigned short* __restrict__ zb, const unsigned short* __restrict__ eb,
    const float* __restrict__ zn, unsigned* __restrict__ dmin) {
  __shared__ __align__(128) unsigned short zlds[2][NROWS * ZD];  // 2 x 16 KB
  // XCD-contiguous remap (grid = 1024, 1024 % 8 == 0 -> bijective):
  const int wg = ((blockIdx.x & 7) << 7) + (blockIdx.x >> 3);
  const int mb = wg & (NMB - 1);   // m-block 0..31
  const int cb = wg >> 5;          // chunk 0..31  (4 consecutive per XCD)
  const int lane = threadIdx.x & 63;
  const int wv = threadIdx.x >> 6;   // 0..3
  const int lr = lane & 15;          // fragment row/col
  const int lg = lane >> 4;          // 0..3 k-group
  const int m0 = mb * MBLK + wv * MW;
  const int nb0 = cb * CHUNK;

  // staging: 16 x 1KB pieces/iter (8 rows each), 4 per wave. Lane l writes
  // LDS byte piece*1024 + l*16 (linear dest); source inverse-swizzled so
  // reads can apply slot ^= (row&7). Piece stride 1024B in global AND LDS.
  const int srow = lane >> 3;           // row within piece, 0..7
  const int sslot = (lane & 7) ^ srow;  // inverse-swizzled 16B slot
  const char* zsrc = (const char*)zb + (size_t)nb0 * 128 +
                     (wv * 32 + srow) * 128 + (sslot << 4);
  char* ldst0 = (char*)&zlds[0][0] + wv * 4096;
  char* ldst1 = (char*)&zlds[1][0] + wv * 4096;

  // B fragments: 4 tiles of 16 m-cols, K=64 in two halves (32 VGPR)
  bf16x8 bfr[4][2];
#pragma unroll
  for (int t = 0; t < 4; ++t)
#pragma unroll
    for (int h = 0; h < 2; ++h)
      bfr[t][h] = *reinterpret_cast<const bf16x8*>(
          &eb[(size_t)(m0 + t * 16 + lr) * ZD + h * 32 + lg * 8]);

  float minv[4] = {3.4e38f, 3.4e38f, 3.4e38f, 3.4e38f};

  auto stage = [&](char* dst, const char* src) {
#pragma unroll
    for (int j = 0; j < 4; ++j)
      __builtin_amdgcn_global_load_lds(
          (const __attribute__((address_space(1))) unsigned int*)(src + j * 1024),
          (__attribute__((address_space(3))) unsigned int*)(dst + j * 1024),
          16, 0, 0);
  };

  const float* znp = zn + nb0;
  const int x0 = (lg * 16) ^ ((lr & 7) << 4);  // swizzled 16B slot, K-half 0

  // 2-deep prefetch: tiles 0 and 1 in flight (4 loads/wave each)
  stage(ldst0, zsrc);
  zsrc += NROWS * 128;
  stage(ldst1, zsrc);
  zsrc += NROWS * 128;

#pragma unroll
  for (int it = 0; it < NITER; ++it) {
    // wait only the stage we need (per-wave), then sync so ALL quarters are in
    if (it + 1 < NITER) { VMW(4); } else { VMW(0); }
    __builtin_amdgcn_s_barrier();

    const char* lbase = (it & 1) ? (const char*)&zlds[1][0] : (const char*)&zlds[0][0];
#pragma unroll
    for (int s = 0; s < NROWS / 16; ++s) {
      const int rb = (s * 16 + lr) * 128;
      bf16x8 a0 = *reinterpret_cast<const bf16x8*>(lbase + rb + x0);
      bf16x8 a1 = *reinterpret_cast<const bf16x8*>(lbase + rb + (x0 ^ 64));
      f32x4 znv = *reinterpret_cast<const f32x4*>(znp + s * 16 + lg * 4);
#pragma unroll
      for (int t = 0; t < 4; ++t) {
        // acc = zn[n] + sum_k z_n[k] * (-2 e_m[k])
        f32x4 acc = __builtin_amdgcn_mfma_f32_16x16x32_bf16(a0, bfr[t][0], znv, 0, 0, 0);
        acc = __builtin_amdgcn_mfma_f32_16x16x32_bf16(a1, bfr[t][1], acc, 0, 0, 0);
        float x = fminf(fminf(acc[0], acc[1]), acc[2]);
        minv[t] = fminf(fminf(x, acc[3]), minv[t]);
      }
    }
    znp += NROWS;

    if (it + 2 < NITER) {
      // all waves done reading this buffer -> safe to restage it with tile it+2
      __builtin_amdgcn_s_barrier();
      stage((it & 1) ? ldst1 : ldst0, zsrc);
      zsrc += NROWS * 128;
    }
  }

  // cross-lane: min over the 4 row-groups (lg); lanes 0..15 hold col lr
#pragma unroll
  for (int t = 0; t < 4; ++t) {
    float v = minv[t];
    v = fminf(v, __shfl_xor(v, 16, 64));
    v = fminf(v, __shfl_xor(v, 32, 64));
    if (lg == 0) {
      unsigned bits = __float_as_uint(v);
      unsigned key = (bits & 0x80000000u) ? ~bits : (bits | 0x80000000u);
      atomicMin(&dmin[m0 + t * 16 + lr], key);  // device-scope, order-inv
    }
  }
}

// ---------------------------------------------------------------------------
// finalize: 32 blocks x 256: sum_m ( en[m] + decode(dmin[m]) ) via
// fixed-point i64 atomic (order-invariant -> deterministic); last block out.
// ---------------------------------------------------------------------------
__global__ __launch_bounds__(256) void finalize(const unsigned* __restrict__ dmin,
                                                const float* __restrict__ en,
                                                unsigned long long* __restrict__ acc,
                                                unsigned* __restrict__ cnt,
                                                float* __restrict__ out) {
  const int m = blockIdx.x * 256 + threadIdx.x;
  unsigned key = dmin[m];
  unsigned bits = (key & 0x80000000u) ? (key & 0x7FFFFFFFu) : ~key;
  float mv = __uint_as_float(bits);
  double s = (double)(mv + en[m]);
  __shared__ double sred[256];
  sred[threadIdx.x] = s;
  __syncthreads();
  for (int off = 128; off > 0; off >>= 1) {
    if ((int)threadIdx.x < off) sred[threadIdx.x] += sred[threadIdx.x + off];
    __syncthreads();
  }
  if (threadIdx.x == 0) {
    unsigned long long iv = (unsigned long long)(sred[0] * SCALE + 0.5);
    atomicAdd(acc, iv);
    __threadfence();
    unsigned d = atomicAdd(cnt, 1u);
    if (d == MM / 256 - 1) {  // last block: all acc-adds happened-before
      __threadfence();
      unsigned long long tot = atomicAdd(acc, 0ULL);
      out[0] = (float)((double)tot / SCALE / (double)MM);
    }
  }
}

extern "C" void kernel_launch(void* const* d_in, const int* in_sizes, int n_in,
                              void* d_out, int out_size, void* d_ws, size_t ws_size,
                              hipStream_t stream) {
  const float* z = (const float*)d_in[0];  // (N, 64) f32
  const float* e = (const float*)d_in[1];  // (M, 64) f32
  float* out = (float*)d_out;

  unsigned short* zb = (unsigned short*)d_ws;          // NN*64 bf16 (4 MB)
  unsigned short* eb = zb + (size_t)NN * ZD;           // MM*64 bf16 (1 MB)
  float* zn = (float*)(eb + (size_t)MM * ZD);          // NN f32
  float* en = zn + NN;                                 // MM f32
  unsigned* dmin = (unsigned*)(en + MM);               // MM u32
  unsigned long long* acc = (unsigned long long*)(dmin + MM);  // 8B
  unsigned* cnt = (unsigned*)(acc + 1);                // 4B

  prep<<<(NN + MM) / 32, 256, 0, stream>>>(z, e, zb, zn, eb, en, dmin, acc, cnt);
  min_dist<<<GRID, 256, 0, stream>>>(zb, eb, zn, dmin);
  finalize<<<MM / 256, 256, 0, stream>>>(dmin, en, acc, cnt, out);
}

// Round 12
// 67.608 us; speedup vs baseline: 2.5259x; 2.5259x over previous
//
#include <hip/hip_runtime.h>
#include <hip/hip_bf16.h>
#include <math.h>

// Problem: N=32768, M=8192, Z=64.  loss = mean_m min_n ||tanh(z_n) - e_m||^2
#define NN 32768
#define MM 8192
#define ZD 64
#define WAVES 4
#define MW 64                  // m-cols per wave (4 x 16-col MFMA tiles)
#define MBLK (WAVES * MW)      // 256 m-cols per block
#define NMB (MM / MBLK)        // 32 m-blocks
#define NCHUNKS 32             // split of N across chunks
#define CHUNK (NN / NCHUNKS)   // 1024
#define NROWS 128              // n-rows staged per iteration
#define NITER (CHUNK / NROWS)  // 8
#define GRID (NMB * NCHUNKS)   // 1024 blocks = 4/CU
#define SCALE 4294967296.0     // 2^32 fixed-point for deterministic sum

// counted vmcnt (T4): keep prefetch loads in flight ACROSS barriers;
// never drain to 0 in the main loop.
#define VMW(N) asm volatile("s_waitcnt vmcnt(" #N ")" ::: "memory")

typedef __attribute__((ext_vector_type(8))) short bf16x8;  // 8 bf16 = 4 VGPR
typedef __attribute__((ext_vector_type(4))) float f32x4;

__device__ inline unsigned short f2bf(float f) {  // RNE f32 -> bf16 (finite)
  unsigned u = __float_as_uint(f);
  return (unsigned short)((u + 0x7fffu + ((u >> 16) & 1u)) >> 16);
}
__device__ inline float bf2f(unsigned short h) {
  return __uint_as_float(((unsigned)h) << 16);
}

// ---------------------------------------------------------------------------
// prep (fused): blocks [0, NN/32) do z-rows; blocks [NN/32, ..) do e-rows and
// re-init dmin/acc/cnt (graph replays leave them dirty).
// ---------------------------------------------------------------------------
__global__ __launch_bounds__(256) void prep(
    const float* __restrict__ z, const float* __restrict__ e,
    unsigned short* __restrict__ zb, float* __restrict__ zn,
    unsigned short* __restrict__ eb, float* __restrict__ en,
    unsigned* __restrict__ dmin, unsigned long long* __restrict__ acc,
    unsigned* __restrict__ cnt) {
  const int q = threadIdx.x & 7;  // 8 f32 each
  if (blockIdx.x < NN / 32) {
    const int row = blockIdx.x * 32 + (threadIdx.x >> 3);
    const size_t base = (size_t)row * ZD + q * 8;
    float4 v0 = *reinterpret_cast<const float4*>(&z[base]);
    float4 v1 = *reinterpret_cast<const float4*>(&z[base + 4]);
    float in[8] = {v0.x, v0.y, v0.z, v0.w, v1.x, v1.y, v1.z, v1.w};
    unsigned short b[8];
    float s = 0.f;
#pragma unroll
    for (int i = 0; i < 8; ++i) {
      b[i] = f2bf(tanhf(in[i]));
      float r = bf2f(b[i]);
      s += r * r;
    }
    *reinterpret_cast<bf16x8*>(&zb[base]) = *reinterpret_cast<bf16x8*>(b);
    s += __shfl_xor(s, 1, 64);
    s += __shfl_xor(s, 2, 64);
    s += __shfl_xor(s, 4, 64);
    if (q == 0) zn[row] = s;
  } else {
    const int row = (blockIdx.x - NN / 32) * 32 + (threadIdx.x >> 3);
    const size_t base = (size_t)row * ZD + q * 8;
    float4 v0 = *reinterpret_cast<const float4*>(&e[base]);
    float4 v1 = *reinterpret_cast<const float4*>(&e[base + 4]);
    float in[8] = {v0.x, v0.y, v0.z, v0.w, v1.x, v1.y, v1.z, v1.w};
    unsigned short b[8];
    float s = 0.f;
#pragma unroll
    for (int i = 0; i < 8; ++i) {
      unsigned short qb = f2bf(in[i]);
      float r = bf2f(qb);
      s += r * r;
      b[i] = f2bf(-2.f * r);  // exact: power-of-2 scale + sign
    }
    *reinterpret_cast<bf16x8*>(&eb[base]) = *reinterpret_cast<bf16x8*>(b);
    s += __shfl_xor(s, 1, 64);
    s += __shfl_xor(s, 2, 64);
    s += __shfl_xor(s, 4, 64);
    if (q == 0) {
      en[row] = s;
      dmin[row] = 0xFFFFFFFFu;  // +inf key
    }
    if (blockIdx.x == NN / 32 && threadIdx.x == 0) {
      *acc = 0ULL;
      *cnt = 0u;
    }
  }
}

// ---------------------------------------------------------------------------
// min_dist: dmin[m] <- atomicMin over n of key( zn[n] - 2*z_n.e_m )
// R8 geometry (1024 blocks = 4/CU, 4 waves x 64 m-cols, 16x16x32 MFMA,
// XOR-swizzled LDS staging -> 0 conflicts, zn in the C-operand) + T4
// counted-vmcnt pipeline: raw s_barrier, vmcnt(4) mid-loop. Outer loop is
// PINNED to unroll 1 — R11's #pragma unroll on this loop octupled live
// ranges, spilled at VGPR=256, 190/345 MB scratch traffic (rule: never
// fully unroll a barriered pipeline loop).
// ---------------------------------------------------------------------------
__global__ __launch_bounds__(256) void min_dist(
    const unsigned short* __restrict__ zb, const unsigned short* __restrict__ eb,
    const float* __restrict__ zn, unsigned* __restrict__ dmin) {
  __shared__ __align__(128) unsigned short zlds[2][NROWS * ZD];  // 2 x 16 KB
  // XCD-contiguous remap (grid = 1024, 1024 % 8 == 0 -> bijective):
  const int wg = ((blockIdx.x & 7) << 7) + (blockIdx.x >> 3);
  const int mb = wg & (NMB - 1);   // m-block 0..31
  const int cb = wg >> 5;          // chunk 0..31  (4 consecutive per XCD)
  const int lane = threadIdx.x & 63;
  const int wv = threadIdx.x >> 6;   // 0..3
  const int lr = lane & 15;          // fragment row/col
  const int lg = lane >> 4;          // 0..3 k-group
  const int m0 = mb * MBLK + wv * MW;
  const int nb0 = cb * CHUNK;

  // staging: 16 x 1KB pieces/iter (8 rows each), 4 per wave. Lane l writes
  // LDS byte piece*1024 + l*16 (linear dest); source inverse-swizzled so
  // reads can apply slot ^= (row&7). Piece stride 1024B in global AND LDS.
  const int srow = lane >> 3;           // row within piece, 0..7
  const int sslot = (lane & 7) ^ srow;  // inverse-swizzled 16B slot
  const char* zsrc = (const char*)zb + (size_t)nb0 * 128 +
                     (wv * 32 + srow) * 128 + (sslot << 4);
  char* ldst0 = (char*)&zlds[0][0] + wv * 4096;
  char* ldst1 = (char*)&zlds[1][0] + wv * 4096;

  // B fragments: 4 tiles of 16 m-cols, K=64 in two halves (32 VGPR)
  bf16x8 bfr[4][2];
#pragma unroll
  for (int t = 0; t < 4; ++t)
#pragma unroll
    for (int h = 0; h < 2; ++h)
      bfr[t][h] = *reinterpret_cast<const bf16x8*>(
          &eb[(size_t)(m0 + t * 16 + lr) * ZD + h * 32 + lg * 8]);

  float minv[4] = {3.4e38f, 3.4e38f, 3.4e38f, 3.4e38f};

  auto stage = [&](char* dst, const char* src) {
#pragma unroll
    for (int j = 0; j < 4; ++j)
      __builtin_amdgcn_global_load_lds(
          (const __attribute__((address_space(1))) unsigned int*)(src + j * 1024),
          (__attribute__((address_space(3))) unsigned int*)(dst + j * 1024),
          16, 0, 0);
  };

  const float* znp = zn + nb0;
  const int x0 = (lg * 16) ^ ((lr & 7) << 4);  // swizzled 16B slot, K-half 0

  // 2-deep prefetch: tiles 0 and 1 in flight (4 loads/wave each)
  stage(ldst0, zsrc);
  zsrc += NROWS * 128;
  stage(ldst1, zsrc);
  zsrc += NROWS * 128;

#pragma unroll 1  // NEVER unroll: barriered pipeline loop (R11 spill lesson)
  for (int it = 0; it < NITER; ++it) {
    // wait only the stage we need (newest stage may stay in flight)
    if (it + 1 < NITER) { VMW(4); } else { VMW(0); }
    __builtin_amdgcn_s_barrier();

    const char* lbase = (it & 1) ? (const char*)&zlds[1][0] : (const char*)&zlds[0][0];
#pragma unroll
    for (int s = 0; s < NROWS / 16; ++s) {
      const int rb = (s * 16 + lr) * 128;
      bf16x8 a0 = *reinterpret_cast<const bf16x8*>(lbase + rb + x0);
      bf16x8 a1 = *reinterpret_cast<const bf16x8*>(lbase + rb + (x0 ^ 64));
      f32x4 znv = *reinterpret_cast<const f32x4*>(znp + s * 16 + lg * 4);
#pragma unroll
      for (int t = 0; t < 4; ++t) {
        // acc = zn[n] + sum_k z_n[k] * (-2 e_m[k])
        f32x4 acc = __builtin_amdgcn_mfma_f32_16x16x32_bf16(a0, bfr[t][0], znv, 0, 0, 0);
        acc = __builtin_amdgcn_mfma_f32_16x16x32_bf16(a1, bfr[t][1], acc, 0, 0, 0);
        float x = fminf(fminf(acc[0], acc[1]), acc[2]);
        minv[t] = fminf(fminf(x, acc[3]), minv[t]);
      }
    }
    znp += NROWS;

    if (it + 2 < NITER) {
      // all waves done reading this buffer -> safe to restage with tile it+2
      __builtin_amdgcn_s_barrier();
      stage((it & 1) ? ldst1 : ldst0, zsrc);
      zsrc += NROWS * 128;
    }
  }

  // cross-lane: min over the 4 row-groups (lg); lanes 0..15 hold col lr
#pragma unroll
  for (int t = 0; t < 4; ++t) {
    float v = minv[t];
    v = fminf(v, __shfl_xor(v, 16, 64));
    v = fminf(v, __shfl_xor(v, 32, 64));
    if (lg == 0) {
      unsigned bits = __float_as_uint(v);
      unsigned key = (bits & 0x80000000u) ? ~bits : (bits | 0x80000000u);
      atomicMin(&dmin[m0 + t * 16 + lr], key);  // device-scope, order-inv
    }
  }
}

// ---------------------------------------------------------------------------
// finalize: 32 blocks x 256: sum_m ( en[m] + decode(dmin[m]) ) via
// fixed-point i64 atomic (order-invariant -> deterministic); last block out.
// ---------------------------------------------------------------------------
__global__ __launch_bounds__(256) void finalize(const unsigned* __restrict__ dmin,
                                                const float* __restrict__ en,
                                                unsigned long long* __restrict__ acc,
                                                unsigned* __restrict__ cnt,
                                                float* __restrict__ out) {
  const int m = blockIdx.x * 256 + threadIdx.x;
  unsigned key = dmin[m];
  unsigned bits = (key & 0x80000000u) ? (key & 0x7FFFFFFFu) : ~key;
  float mv = __uint_as_float(bits);
  double s = (double)(mv + en[m]);
  __shared__ double sred[256];
  sred[threadIdx.x] = s;
  __syncthreads();
  for (int off = 128; off > 0; off >>= 1) {
    if ((int)threadIdx.x < off) sred[threadIdx.x] += sred[threadIdx.x + off];
    __syncthreads();
  }
  if (threadIdx.x == 0) {
    unsigned long long iv = (unsigned long long)(sred[0] * SCALE + 0.5);
    atomicAdd(acc, iv);
    __threadfence();
    unsigned d = atomicAdd(cnt, 1u);
    if (d == MM / 256 - 1) {  // last block: all acc-adds happened-before
      __threadfence();
      unsigned long long tot = atomicAdd(acc, 0ULL);
      out[0] = (float)((double)tot / SCALE / (double)MM);
    }
  }
}

extern "C" void kernel_launch(void* const* d_in, const int* in_sizes, int n_in,
                              void* d_out, int out_size, void* d_ws, size_t ws_size,
                              hipStream_t stream) {
  const float* z = (const float*)d_in[0];  // (N, 64) f32
  const float* e = (const float*)d_in[1];  // (M, 64) f32
  float* out = (float*)d_out;

  unsigned short* zb = (unsigned short*)d_ws;          // NN*64 bf16 (4 MB)
  unsigned short* eb = zb + (size_t)NN * ZD;           // MM*64 bf16 (1 MB)
  float* zn = (float*)(eb + (size_t)MM * ZD);          // NN f32
  float* en = zn + NN;                                 // MM f32
  unsigned* dmin = (unsigned*)(en + MM);               // MM u32
  unsigned long long* acc = (unsigned long long*)(dmin + MM);  // 8B
  unsigned* cnt = (unsigned*)(acc + 1);                // 4B

  prep<<<(NN + MM) / 32, 256, 0, stream>>>(z, e, zb, zn, eb, en, dmin, acc, cnt);
  min_dist<<<GRID, 256, 0, stream>>>(zb, eb, zn, dmin);
  finalize<<<MM / 256, 256, 0, stream>>>(dmin, en, acc, cnt, out);
}

// Round 14
// 48.927 us; speedup vs baseline: 3.4903x; 1.3818x over previous
//
#include <hip/hip_runtime.h>
#include <hip/hip_bf16.h>
#include <math.h>

// Problem: N=32768, M=8192, Z=64.  loss = mean_m min_n ||tanh(z_n) - e_m||^2
#define NN 32768
#define MM 8192
#define ZD 64
#define WAVES 4
#define MW 64                  // m-cols per wave (4 x 16-col MFMA tiles)
#define MBLK (WAVES * MW)      // 256 m-cols per block
#define NMB (MM / MBLK)        // 32 m-blocks
#define NCHUNKS 32             // split of N across chunks
#define CHUNK (NN / NCHUNKS)   // 1024
#define NROWS 128              // n-rows staged per iteration
#define NITER (CHUNK / NROWS)  // 8
#define GRID (NMB * NCHUNKS)   // 1024 blocks = 4/CU
#define SCALE 4294967296.0     // 2^32 fixed-point for deterministic sum

typedef __attribute__((ext_vector_type(8))) short bf16x8;  // 8 bf16 = 4 VGPR
typedef __attribute__((ext_vector_type(4))) float f32x4;

__device__ inline unsigned short f2bf(float f) {  // RNE f32 -> bf16 (finite)
  unsigned u = __float_as_uint(f);
  return (unsigned short)((u + 0x7fffu + ((u >> 16) & 1u)) >> 16);
}
__device__ inline float bf2f(unsigned short h) {
  return __uint_as_float(((unsigned)h) << 16);
}
// fast tanh: 1 - 2/(exp2(2x*log2e)+1). v_exp_f32 + v_rcp_f32 (~5 ops vs
// ~20+ for libm tanhf). Saturates correctly: x>>0 -> exp2=inf -> 1;
// x<<0 -> exp2=0 -> -1. Error ~1e-6 << bf16 quantization (4e-3).
__device__ inline float fast_tanh(float x) {
  float r = __builtin_amdgcn_exp2f(x * 2.8853900817779268f);  // 2^(2x*log2e)
  return fmaf(-2.f, __builtin_amdgcn_rcpf(r + 1.f), 1.f);
}

// ---------------------------------------------------------------------------
// prep (fused): blocks [0, NN/32) do z-rows; blocks [NN/32, ..) do e-rows and
// re-init dmin/acc/cnt (graph replays leave them dirty).
//   z: zb[n][k] = bf16(tanh(z[n][k])), zn[n] = sum(quantized^2)
//   e: q = bf16(e); eb[m][k] = bf16(-2*q) (exact); en[m] = sum q^2
// ---------------------------------------------------------------------------
__global__ __launch_bounds__(256) void prep(
    const float* __restrict__ z, const float* __restrict__ e,
    unsigned short* __restrict__ zb, float* __restrict__ zn,
    unsigned short* __restrict__ eb, float* __restrict__ en,
    unsigned* __restrict__ dmin, unsigned long long* __restrict__ acc,
    unsigned* __restrict__ cnt) {
  const int q = threadIdx.x & 7;  // 8 f32 each
  if (blockIdx.x < NN / 32) {
    const int row = blockIdx.x * 32 + (threadIdx.x >> 3);
    const size_t base = (size_t)row * ZD + q * 8;
    float4 v0 = *reinterpret_cast<const float4*>(&z[base]);
    float4 v1 = *reinterpret_cast<const float4*>(&z[base + 4]);
    float in[8] = {v0.x, v0.y, v0.z, v0.w, v1.x, v1.y, v1.z, v1.w};
    unsigned short b[8];
    float s = 0.f;
#pragma unroll
    for (int i = 0; i < 8; ++i) {
      b[i] = f2bf(fast_tanh(in[i]));
      float r = bf2f(b[i]);
      s += r * r;
    }
    *reinterpret_cast<bf16x8*>(&zb[base]) = *reinterpret_cast<bf16x8*>(b);
    s += __shfl_xor(s, 1, 64);
    s += __shfl_xor(s, 2, 64);
    s += __shfl_xor(s, 4, 64);
    if (q == 0) zn[row] = s;
  } else {
    const int row = (blockIdx.x - NN / 32) * 32 + (threadIdx.x >> 3);
    const size_t base = (size_t)row * ZD + q * 8;
    float4 v0 = *reinterpret_cast<const float4*>(&e[base]);
    float4 v1 = *reinterpret_cast<const float4*>(&e[base + 4]);
    float in[8] = {v0.x, v0.y, v0.z, v0.w, v1.x, v1.y, v1.z, v1.w};
    unsigned short b[8];
    float s = 0.f;
#pragma unroll
    for (int i = 0; i < 8; ++i) {
      unsigned short qb = f2bf(in[i]);
      float r = bf2f(qb);
      s += r * r;
      b[i] = f2bf(-2.f * r);  // exact: power-of-2 scale + sign
    }
    *reinterpret_cast<bf16x8*>(&eb[base]) = *reinterpret_cast<bf16x8*>(b);
    s += __shfl_xor(s, 1, 64);
    s += __shfl_xor(s, 2, 64);
    s += __shfl_xor(s, 4, 64);
    if (q == 0) {
      en[row] = s;
      dmin[row] = 0xFFFFFFFFu;  // +inf key
    }
    if (blockIdx.x == NN / 32 && threadIdx.x == 0) {
      *acc = 0ULL;
      *cnt = 0u;
    }
  }
}

// ---------------------------------------------------------------------------
// min_dist: dmin[m] <- atomicMin over n of key( zn[n] - 2*z_n.e_m )
// == R8's proven kernel (46.6 µs total; counted-vmcnt/raw-barrier variants
// R11/R12 regressed: VGPR 152-256, occupancy 10%, one 25ms dispatch).
// 1024 blocks (4/CU), 4 waves x 64 m-cols (4 x 16-col 16x16x32 MFMA tiles,
// f32x4 accs in VGPRs). A-tile (128 n-rows) via LDS: global_load_lds(16B)
// double-buffered, XOR-swizzled (linear LDS dest + inverse-swizzled global
// source + swizzled ds_read_b128 -> 0 conflicts). zn folded into the MFMA
// C-operand. Ordered-uint atomicMin: deterministic. XCD-bijective remap.
// ---------------------------------------------------------------------------
__global__ __launch_bounds__(256) void min_dist(
    const unsigned short* __restrict__ zb, const unsigned short* __restrict__ eb,
    const float* __restrict__ zn, unsigned* __restrict__ dmin) {
  __shared__ __align__(128) unsigned short zlds[2][NROWS * ZD];  // 2 x 16 KB
  // XCD-contiguous remap (grid = 1024, 1024 % 8 == 0 -> bijective):
  const int wg = ((blockIdx.x & 7) << 7) + (blockIdx.x >> 3);
  const int mb = wg & (NMB - 1);   // m-block 0..31
  const int cb = wg >> 5;          // chunk 0..31  (4 consecutive per XCD)
  const int lane = threadIdx.x & 63;
  const int wv = threadIdx.x >> 6;   // 0..3
  const int lr = lane & 15;          // fragment row/col
  const int lg = lane >> 4;          // 0..3 k-group
  const int m0 = mb * MBLK + wv * MW;
  const int nb0 = cb * CHUNK;

  // staging: 16 x 1KB pieces/iter (8 rows each), 4 per wave. Lane l writes
  // LDS byte piece*1024 + l*16 (linear dest); source inverse-swizzled so
  // reads can apply slot ^= (row&7). Piece stride 1024B in global AND LDS.
  const int srow = lane >> 3;           // row within piece, 0..7
  const int sslot = (lane & 7) ^ srow;  // inverse-swizzled 16B slot
  const char* zsrc = (const char*)zb + (size_t)nb0 * 128 +
                     (wv * 32 + srow) * 128 + (sslot << 4);
  char* ldst0 = (char*)&zlds[0][0] + wv * 4096;
  char* ldst1 = (char*)&zlds[1][0] + wv * 4096;

  // B fragments: 4 tiles of 16 m-cols, K=64 in two halves (32 VGPR)
  bf16x8 bfr[4][2];
#pragma unroll
  for (int t = 0; t < 4; ++t)
#pragma unroll
    for (int h = 0; h < 2; ++h)
      bfr[t][h] = *reinterpret_cast<const bf16x8*>(
          &eb[(size_t)(m0 + t * 16 + lr) * ZD + h * 32 + lg * 8]);

  float minv[4] = {3.4e38f, 3.4e38f, 3.4e38f, 3.4e38f};

  auto stage = [&](char* dst, const char* src) {
#pragma unroll
    for (int j = 0; j < 4; ++j)
      __builtin_amdgcn_global_load_lds(
          (const __attribute__((address_space(1))) unsigned int*)(src + j * 1024),
          (__attribute__((address_space(3))) unsigned int*)(dst + j * 1024),
          16, 0, 0);
  };

  const float* znp = zn + nb0;
  const int x0 = (lg * 16) ^ ((lr & 7) << 4);  // swizzled 16B slot, K-half 0

  stage(ldst0, zsrc);
  zsrc += NROWS * 128;
  __syncthreads();  // vmcnt(0) drain before s_barrier

#pragma unroll 1  // never unroll a barriered pipeline loop (R11 spill lesson)
  for (int it = 0; it < NITER; ++it) {
    const char* lbase = (it & 1) ? (const char*)&zlds[1][0] : (const char*)&zlds[0][0];
    if (it + 1 < NITER) {
      stage((it & 1) ? ldst0 : ldst1, zsrc);
      zsrc += NROWS * 128;
    }
#pragma unroll
    for (int s = 0; s < NROWS / 16; ++s) {
      const int rb = (s * 16 + lr) * 128;
      bf16x8 a0 = *reinterpret_cast<const bf16x8*>(lbase + rb + x0);
      bf16x8 a1 = *reinterpret_cast<const bf16x8*>(lbase + rb + (x0 ^ 64));
      f32x4 znv = *reinterpret_cast<const f32x4*>(znp + s * 16 + lg * 4);
#pragma unroll
      for (int t = 0; t < 4; ++t) {
        // acc = zn[n] + sum_k z_n[k] * (-2 e_m[k])
        f32x4 acc = __builtin_amdgcn_mfma_f32_16x16x32_bf16(a0, bfr[t][0], znv, 0, 0, 0);
        acc = __builtin_amdgcn_mfma_f32_16x16x32_bf16(a1, bfr[t][1], acc, 0, 0, 0);
        // two v_min3-fusable triples: min(acc[0..3], running)
        float x = fminf(fminf(acc[0], acc[1]), acc[2]);
        minv[t] = fminf(fminf(x, acc[3]), minv[t]);
      }
    }
    znp += NROWS;
    __syncthreads();  // next-stage landed; prev buf safe to overwrite
  }

  // cross-lane: min over the 4 row-groups (lg); lanes 0..15 hold col lr
#pragma unroll
  for (int t = 0; t < 4; ++t) {
    float v = minv[t];
    v = fminf(v, __shfl_xor(v, 16, 64));
    v = fminf(v, __shfl_xor(v, 32, 64));
    if (lg == 0) {
      unsigned bits = __float_as_uint(v);
      unsigned key = (bits & 0x80000000u) ? ~bits : (bits | 0x80000000u);
      atomicMin(&dmin[m0 + t * 16 + lr], key);  // device-scope, order-inv
    }
  }
}

// ---------------------------------------------------------------------------
// finalize: 32 blocks x 256: sum_m ( en[m] + decode(dmin[m]) ) via
// fixed-point i64 atomic (order-invariant -> deterministic); last block out.
// ---------------------------------------------------------------------------
__global__ __launch_bounds__(256) void finalize(const unsigned* __restrict__ dmin,
                                                const float* __restrict__ en,
                                                unsigned long long* __restrict__ acc,
                                                unsigned* __restrict__ cnt,
                                                float* __restrict__ out) {
  const int m = blockIdx.x * 256 + threadIdx.x;
  unsigned key = dmin[m];
  unsigned bits = (key & 0x80000000u) ? (key & 0x7FFFFFFFu) : ~key;
  float mv = __uint_as_float(bits);
  double s = (double)(mv + en[m]);
  __shared__ double sred[256];
  sred[threadIdx.x] = s;
  __syncthreads();
  for (int off = 128; off > 0; off >>= 1) {
    if ((int)threadIdx.x < off) sred[threadIdx.x] += sred[threadIdx.x + off];
    __syncthreads();
  }
  if (threadIdx.x == 0) {
    unsigned long long iv = (unsigned long long)(sred[0] * SCALE + 0.5);
    atomicAdd(acc, iv);
    __threadfence();
    unsigned d = atomicAdd(cnt, 1u);
    if (d == MM / 256 - 1) {  // last block: all acc-adds happened-before
      __threadfence();
      unsigned long long tot = atomicAdd(acc, 0ULL);
      out[0] = (float)((double)tot / SCALE / (double)MM);
    }
  }
}

extern "C" void kernel_launch(void* const* d_in, const int* in_sizes, int n_in,
                              void* d_out, int out_size, void* d_ws, size_t ws_size,
                              hipStream_t stream) {
  const float* z = (const float*)d_in[0];  // (N, 64) f32
  const float* e = (const float*)d_in[1];  // (M, 64) f32
  float* out = (float*)d_out;

  unsigned short* zb = (unsigned short*)d_ws;          // NN*64 bf16 (4 MB)
  unsigned short* eb = zb + (size_t)NN * ZD;           // MM*64 bf16 (1 MB)
  float* zn = (float*)(eb + (size_t)MM * ZD);          // NN f32
  float* en = zn + NN;                                 // MM f32
  unsigned* dmin = (unsigned*)(en + MM);               // MM u32
  unsigned long long* acc = (unsigned long long*)(dmin + MM);  // 8B
  unsigned* cnt = (unsigned*)(acc + 1);                // 4B

  prep<<<(NN + MM) / 32, 256, 0, stream>>>(z, e, zb, zn, eb, en, dmin, acc, cnt);
  min_dist<<<GRID, 256, 0, stream>>>(zb, eb, zn, dmin);
  finalize<<<MM / 256, 256, 0, stream>>>(dmin, en, acc, cnt, out);
}

// Round 15
// 47.293 us; speedup vs baseline: 3.6109x; 1.0346x over previous
//
#include <hip/hip_runtime.h>
#include <hip/hip_bf16.h>
#include <math.h>

// Problem: N=32768, M=8192, Z=64.  loss = mean_m min_n ||tanh(z_n) - e_m||^2
#define NN 32768
#define MM 8192
#define ZD 64
#define WAVES 4
#define MW 64                  // m-cols per wave (4 x 16-col MFMA tiles)
#define MBLK (WAVES * MW)      // 256 m-cols per block
#define NMB (MM / MBLK)        // 32 m-blocks
#define NCHUNKS 64             // split of N across chunks
#define CHUNK (NN / NCHUNKS)   // 512
#define NROWS 64               // n-rows staged per iteration (16 KB LDS tot)
#define NITER (CHUNK / NROWS)  // 8
#define GRID (NMB * NCHUNKS)   // 2048 blocks = 8/CU (LDS 16KB, VGPR 44)
#define SCALE 4294967296.0     // 2^32 fixed-point for deterministic sum

typedef __attribute__((ext_vector_type(8))) short bf16x8;  // 8 bf16 = 4 VGPR
typedef __attribute__((ext_vector_type(4))) float f32x4;

__device__ inline unsigned short f2bf(float f) {  // RNE f32 -> bf16 (finite)
  unsigned u = __float_as_uint(f);
  return (unsigned short)((u + 0x7fffu + ((u >> 16) & 1u)) >> 16);
}
__device__ inline float bf2f(unsigned short h) {
  return __uint_as_float(((unsigned)h) << 16);
}
// fast tanh: 1 - 2/(exp2(2x*log2e)+1). v_exp_f32 + v_rcp_f32. Saturates
// correctly at +-1; error ~1e-6 << bf16 quantization (4e-3).
__device__ inline float fast_tanh(float x) {
  float r = __builtin_amdgcn_exp2f(x * 2.8853900817779268f);  // 2^(2x*log2e)
  return fmaf(-2.f, __builtin_amdgcn_rcpf(r + 1.f), 1.f);
}

// ---------------------------------------------------------------------------
// prep (fused): blocks [0, NN/32) do z-rows; blocks [NN/32, ..) do e-rows and
// re-init dmin/acc/cnt (graph replays leave them dirty).
// ---------------------------------------------------------------------------
__global__ __launch_bounds__(256) void prep(
    const float* __restrict__ z, const float* __restrict__ e,
    unsigned short* __restrict__ zb, float* __restrict__ zn,
    unsigned short* __restrict__ eb, float* __restrict__ en,
    unsigned* __restrict__ dmin, unsigned long long* __restrict__ acc,
    unsigned* __restrict__ cnt) {
  const int q = threadIdx.x & 7;  // 8 f32 each
  if (blockIdx.x < NN / 32) {
    const int row = blockIdx.x * 32 + (threadIdx.x >> 3);
    const size_t base = (size_t)row * ZD + q * 8;
    float4 v0 = *reinterpret_cast<const float4*>(&z[base]);
    float4 v1 = *reinterpret_cast<const float4*>(&z[base + 4]);
    float in[8] = {v0.x, v0.y, v0.z, v0.w, v1.x, v1.y, v1.z, v1.w};
    unsigned short b[8];
    float s = 0.f;
#pragma unroll
    for (int i = 0; i < 8; ++i) {
      b[i] = f2bf(fast_tanh(in[i]));
      float r = bf2f(b[i]);
      s += r * r;
    }
    *reinterpret_cast<bf16x8*>(&zb[base]) = *reinterpret_cast<bf16x8*>(b);
    s += __shfl_xor(s, 1, 64);
    s += __shfl_xor(s, 2, 64);
    s += __shfl_xor(s, 4, 64);
    if (q == 0) zn[row] = s;
  } else {
    const int row = (blockIdx.x - NN / 32) * 32 + (threadIdx.x >> 3);
    const size_t base = (size_t)row * ZD + q * 8;
    float4 v0 = *reinterpret_cast<const float4*>(&e[base]);
    float4 v1 = *reinterpret_cast<const float4*>(&e[base + 4]);
    float in[8] = {v0.x, v0.y, v0.z, v0.w, v1.x, v1.y, v1.z, v1.w};
    unsigned short b[8];
    float s = 0.f;
#pragma unroll
    for (int i = 0; i < 8; ++i) {
      unsigned short qb = f2bf(in[i]);
      float r = bf2f(qb);
      s += r * r;
      b[i] = f2bf(-2.f * r);  // exact: power-of-2 scale + sign
    }
    *reinterpret_cast<bf16x8*>(&eb[base]) = *reinterpret_cast<bf16x8*>(b);
    s += __shfl_xor(s, 1, 64);
    s += __shfl_xor(s, 2, 64);
    s += __shfl_xor(s, 4, 64);
    if (q == 0) {
      en[row] = s;
      dmin[row] = 0xFFFFFFFFu;  // +inf key
    }
    if (blockIdx.x == NN / 32 && threadIdx.x == 0) {
      *acc = 0ULL;
      *cnt = 0u;
    }
  }
}

// ---------------------------------------------------------------------------
// min_dist: dmin[m] <- atomicMin over n of key( zn[n] - 2*z_n.e_m )
// R14 core with halved block footprint: NROWS 64 (16 KB LDS) x NCHUNKS 64
// -> 2048 blocks = 8/CU (R14: 4/CU, Occupancy 31%, ~35% idle = per-block
// barrier drains with too few neighbor blocks to hide them). 4 waves x 64
// m-cols (16x16x32 MFMA, f32x4 accs in VGPRs, VGPR=44). A-tile via
// global_load_lds(16B) double-buffered, XOR-swizzled -> 0 conflicts. zn in
// the MFMA C-operand. Ordered-uint atomicMin. XCD-bijective remap (>>8).
// ---------------------------------------------------------------------------
__global__ __launch_bounds__(256) void min_dist(
    const unsigned short* __restrict__ zb, const unsigned short* __restrict__ eb,
    const float* __restrict__ zn, unsigned* __restrict__ dmin) {
  __shared__ __align__(128) unsigned short zlds[2][NROWS * ZD];  // 2 x 8 KB
  // XCD-contiguous remap (grid = 2048, 2048 % 8 == 0 -> bijective):
  const int wg = ((blockIdx.x & 7) << 8) + (blockIdx.x >> 3);
  const int mb = wg & (NMB - 1);   // m-block 0..31
  const int cb = wg >> 5;          // chunk 0..63  (8 consecutive per XCD)
  const int lane = threadIdx.x & 63;
  const int wv = threadIdx.x >> 6;   // 0..3
  const int lr = lane & 15;          // fragment row/col
  const int lg = lane >> 4;          // 0..3 k-group
  const int m0 = mb * MBLK + wv * MW;
  const int nb0 = cb * CHUNK;

  // staging: 8 x 1KB pieces/iter (8 rows each), 2 per wave. Lane l writes
  // LDS byte piece*1024 + l*16 (linear dest); source inverse-swizzled so
  // reads can apply slot ^= (row&7). Piece stride 1024B in global AND LDS.
  const int srow = lane >> 3;           // row within piece, 0..7
  const int sslot = (lane & 7) ^ srow;  // inverse-swizzled 16B slot
  const char* zsrc = (const char*)zb + (size_t)nb0 * 128 +
                     (wv * 16 + srow) * 128 + (sslot << 4);
  char* ldst0 = (char*)&zlds[0][0] + wv * 2048;
  char* ldst1 = (char*)&zlds[1][0] + wv * 2048;

  // B fragments: 4 tiles of 16 m-cols, K=64 in two halves (32 VGPR)
  bf16x8 bfr[4][2];
#pragma unroll
  for (int t = 0; t < 4; ++t)
#pragma unroll
    for (int h = 0; h < 2; ++h)
      bfr[t][h] = *reinterpret_cast<const bf16x8*>(
          &eb[(size_t)(m0 + t * 16 + lr) * ZD + h * 32 + lg * 8]);

  float minv[4] = {3.4e38f, 3.4e38f, 3.4e38f, 3.4e38f};

  auto stage = [&](char* dst, const char* src) {
#pragma unroll
    for (int j = 0; j < 2; ++j)
      __builtin_amdgcn_global_load_lds(
          (const __attribute__((address_space(1))) unsigned int*)(src + j * 1024),
          (__attribute__((address_space(3))) unsigned int*)(dst + j * 1024),
          16, 0, 0);
  };

  const float* znp = zn + nb0;
  const int x0 = (lg * 16) ^ ((lr & 7) << 4);  // swizzled 16B slot, K-half 0

  stage(ldst0, zsrc);
  zsrc += NROWS * 128;
  __syncthreads();  // vmcnt(0) drain before s_barrier

#pragma unroll 1  // never unroll a barriered pipeline loop (R11 spill lesson)
  for (int it = 0; it < NITER; ++it) {
    const char* lbase = (it & 1) ? (const char*)&zlds[1][0] : (const char*)&zlds[0][0];
    if (it + 1 < NITER) {
      stage((it & 1) ? ldst0 : ldst1, zsrc);
      zsrc += NROWS * 128;
    }
#pragma unroll
    for (int s = 0; s < NROWS / 16; ++s) {
      const int rb = (s * 16 + lr) * 128;
      bf16x8 a0 = *reinterpret_cast<const bf16x8*>(lbase + rb + x0);
      bf16x8 a1 = *reinterpret_cast<const bf16x8*>(lbase + rb + (x0 ^ 64));
      f32x4 znv = *reinterpret_cast<const f32x4*>(znp + s * 16 + lg * 4);
#pragma unroll
      for (int t = 0; t < 4; ++t) {
        // acc = zn[n] + sum_k z_n[k] * (-2 e_m[k])
        f32x4 acc = __builtin_amdgcn_mfma_f32_16x16x32_bf16(a0, bfr[t][0], znv, 0, 0, 0);
        acc = __builtin_amdgcn_mfma_f32_16x16x32_bf16(a1, bfr[t][1], acc, 0, 0, 0);
        // two v_min3-fusable triples: min(acc[0..3], running)
        float x = fminf(fminf(acc[0], acc[1]), acc[2]);
        minv[t] = fminf(fminf(x, acc[3]), minv[t]);
      }
    }
    znp += NROWS;
    __syncthreads();  // next-stage landed; prev buf safe to overwrite
  }

  // cross-lane: min over the 4 row-groups (lg); lanes 0..15 hold col lr
#pragma unroll
  for (int t = 0; t < 4; ++t) {
    float v = minv[t];
    v = fminf(v, __shfl_xor(v, 16, 64));
    v = fminf(v, __shfl_xor(v, 32, 64));
    if (lg == 0) {
      unsigned bits = __float_as_uint(v);
      unsigned key = (bits & 0x80000000u) ? ~bits : (bits | 0x80000000u);
      atomicMin(&dmin[m0 + t * 16 + lr], key);  // device-scope, order-inv
    }
  }
}

// ---------------------------------------------------------------------------
// finalize: 32 blocks x 256: sum_m ( en[m] + decode(dmin[m]) ) via
// fixed-point i64 atomic (order-invariant -> deterministic); last block out.
// ---------------------------------------------------------------------------
__global__ __launch_bounds__(256) void finalize(const unsigned* __restrict__ dmin,
                                                const float* __restrict__ en,
                                                unsigned long long* __restrict__ acc,
                                                unsigned* __restrict__ cnt,
                                                float* __restrict__ out) {
  const int m = blockIdx.x * 256 + threadIdx.x;
  unsigned key = dmin[m];
  unsigned bits = (key & 0x80000000u) ? (key & 0x7FFFFFFFu) : ~key;
  float mv = __uint_as_float(bits);
  double s = (double)(mv + en[m]);
  __shared__ double sred[256];
  sred[threadIdx.x] = s;
  __syncthreads();
  for (int off = 128; off > 0; off >>= 1) {
    if ((int)threadIdx.x < off) sred[threadIdx.x] += sred[threadIdx.x + off];
    __syncthreads();
  }
  if (threadIdx.x == 0) {
    unsigned long long iv = (unsigned long long)(sred[0] * SCALE + 0.5);
    atomicAdd(acc, iv);
    __threadfence();
    unsigned d = atomicAdd(cnt, 1u);
    if (d == MM / 256 - 1) {  // last block: all acc-adds happened-before
      __threadfence();
      unsigned long long tot = atomicAdd(acc, 0ULL);
      out[0] = (float)((double)tot / SCALE / (double)MM);
    }
  }
}

extern "C" void kernel_launch(void* const* d_in, const int* in_sizes, int n_in,
                              void* d_out, int out_size, void* d_ws, size_t ws_size,
                              hipStream_t stream) {
  const float* z = (const float*)d_in[0];  // (N, 64) f32
  const float* e = (const float*)d_in[1];  // (M, 64) f32
  float* out = (float*)d_out;

  unsigned short* zb = (unsigned short*)d_ws;          // NN*64 bf16 (4 MB)
  unsigned short* eb = zb + (size_t)NN * ZD;           // MM*64 bf16 (1 MB)
  float* zn = (float*)(eb + (size_t)MM * ZD);          // NN f32
  float* en = zn + NN;                                 // MM f32
  unsigned* dmin = (unsigned*)(en + MM);               // MM u32
  unsigned long long* acc = (unsigned long long*)(dmin + MM);  // 8B
  unsigned* cnt = (unsigned*)(acc + 1);                // 4B

  prep<<<(NN + MM) / 32, 256, 0, stream>>>(z, e, zb, zn, eb, en, dmin, acc, cnt);
  min_dist<<<GRID, 256, 0, stream>>>(zb, eb, zn, dmin);
  finalize<<<MM / 256, 256, 0, stream>>>(dmin, en, acc, cnt, out);
}